// Round 7
// baseline (2246.862 us; speedup 1.0000x reference)
//
#include <hip/hip_runtime.h>

typedef unsigned short u16;
typedef unsigned int   u32;
typedef __bf16  bf16x8 __attribute__((ext_vector_type(8)));
typedef float   f32x4  __attribute__((ext_vector_type(4)));

#define B_ 8192
#define DI __device__ __forceinline__

DI u16 f2bf(float f) {
  u32 u = __float_as_uint(f);
  u = (u + 0x7fffu + ((u >> 16) & 1u)) >> 16;   // RNE
  return (u16)u;
}
DI float bf2f(u16 h) { return __uint_as_float(((u32)h) << 16); }

// async global->LDS, 16B per lane; LDS dest = wave-uniform base + lane*16
DI void gll(const u16* g, u16* l) {
  __builtin_amdgcn_global_load_lds(
      (const __attribute__((address_space(1))) void*)g,
      (__attribute__((address_space(3))) void*)l, 16, 0, 0);
}

// ---------------- weight transpose + cast: W[g][K][N] f32 -> Wt[g][N][K] bf16
__global__ __launch_bounds__(256) void transpose_cast(
    const float* __restrict__ W, u16* __restrict__ Wt, int K, int N) {
  __shared__ float tile[64][65];
  int g = blockIdx.z;
  int k0 = blockIdx.x * 64, n0 = blockIdx.y * 64;
  const float* Wg = W + (size_t)g * K * N;
  u16* Og = Wt + (size_t)g * N * K;
  int tid = threadIdx.x;
  int rr = tid >> 4, cc = (tid & 15) * 4;
#pragma unroll
  for (int r = 0; r < 4; ++r) {
    int k = rr + r * 16;
    float4 v = *(const float4*)(Wg + (size_t)(k0 + k) * N + n0 + cc);
    tile[k][cc] = v.x; tile[k][cc + 1] = v.y; tile[k][cc + 2] = v.z; tile[k][cc + 3] = v.w;
  }
  __syncthreads();
  int nr = tid >> 3, kc = (tid & 7) * 8;
#pragma unroll
  for (int p = 0; p < 2; ++p) {
    int n = nr + p * 32;
    u16 tmp[8];
#pragma unroll
    for (int j = 0; j < 8; ++j) tmp[j] = f2bf(tile[kc + j][n]);
    *(uint4*)(Og + (size_t)(n0 + n) * K + k0 + kc) = *(uint4*)tmp;
  }
}

// ---------------- f32 -> bf16 cast (4 elems/thread)
__global__ __launch_bounds__(256) void cast_bf16k(const float* __restrict__ X, u16* __restrict__ Y) {
  size_t i = ((size_t)blockIdx.x * 256 + threadIdx.x) * 4;
  float4 v = *(const float4*)(X + i);
  u16 t[4] = { f2bf(v.x), f2bf(v.y), f2bf(v.z), f2bf(v.w) };
  *(uint2*)(Y + i) = *(uint2*)t;
}

// ---------------- batched bf16 GEMM, templated N-tile (128 or 64)
// A select: (a_g0 + z)/a_div picks A matrix (stride a_stride elems); A pre-offset to chunk row
// Wt: [z][N][K] bf16; bias: [z][N]; C pre-offset to chunk row; C + z*c_stride
#define BM 128
#define BK 32
#define LDK 32   // unpadded: required by global_load_lds lane mapping

template<int BN_>
__global__ __launch_bounds__(256) void gemm_t(
    const u16* __restrict__ A, long a_stride, int a_div, int a_g0,
    const u16* __restrict__ Wt, const float* __restrict__ bias,
    u16* __restrict__ C, long c_stride, int N, int K, int relu_flag) {
  constexpr int JT = BN_ / 32;       // B sub-tiles per wave (4 or 2)
  constexpr int BROWS = BN_ / 4;     // B rows staged per wave (32 or 16)
  int gz = blockIdx.z;
  const u16* Ag = A + (size_t)((a_g0 + gz) / a_div) * a_stride;
  const u16* Wg = Wt + (size_t)gz * N * K;
  u16* Cg = C + (size_t)gz * c_stride;
  int m0 = blockIdx.x * BM, n0 = blockIdx.y * BN_;

  __shared__ __align__(16) u16 As[BM * LDK];
  __shared__ __align__(16) u16 Bs[BN_ * LDK];

  int tid = threadIdx.x;
  int wv = tid >> 6, ln = tid & 63;
  int wm = (wv >> 1) * 64, wn = (wv & 1) * (BN_ / 2);
  int lr = ln & 15, lk = (ln >> 4) * 8;

  int sr = ln >> 2;           // 0..15
  int sc = (ln & 3) * 8;      // u16 col 0,8,16,24
  const u16* aG = Ag + (size_t)(m0 + wv * 32 + sr) * K + sc;
  const u16* bG = Wg + (size_t)(n0 + wv * BROWS + sr) * K + sc;
  u16* aL0 = As + (wv * 32) * LDK;
  u16* aL1 = aL0 + 16 * LDK;
  u16* bL0 = Bs + (wv * BROWS) * LDK;

  f32x4 acc[4][JT];
#pragma unroll
  for (int i = 0; i < 4; ++i)
#pragma unroll
    for (int j = 0; j < JT; ++j)
      acc[i][j] = (f32x4){0.f, 0.f, 0.f, 0.f};

  int nk = K / BK;
  for (int ks = 0; ks < nk; ++ks) {
    __syncthreads();
    gll(aG + ks * BK, aL0);
    gll(aG + ks * BK + (size_t)16 * K, aL1);
    gll(bG + ks * BK, bL0);
    if (BN_ == 128) gll(bG + ks * BK + (size_t)16 * K, bL0 + 16 * LDK);
    __syncthreads();
    bf16x8 af[4], bfr[JT];
#pragma unroll
    for (int i = 0; i < 4; ++i) {
      union { uint4 u; bf16x8 v; } ua;
      ua.u = *(const uint4*)(As + (wm + i * 16 + lr) * LDK + lk);
      af[i] = ua.v;
    }
#pragma unroll
    for (int j = 0; j < JT; ++j) {
      union { uint4 u; bf16x8 v; } ub;
      ub.u = *(const uint4*)(Bs + (wn + j * 16 + lr) * LDK + lk);
      bfr[j] = ub.v;
    }
#pragma unroll
    for (int i = 0; i < 4; ++i)
#pragma unroll
      for (int j = 0; j < JT; ++j)
        acc[i][j] = __builtin_amdgcn_mfma_f32_16x16x32_bf16(af[i], bfr[j], acc[i][j], 0, 0, 0);
  }

  int mr = (ln >> 4) * 4;
#pragma unroll
  for (int i = 0; i < 4; ++i) {
#pragma unroll
    for (int j = 0; j < JT; ++j) {
      int n = n0 + wn + j * 16 + lr;
      float bv = bias[(size_t)gz * N + n];
#pragma unroll
      for (int r = 0; r < 4; ++r) {
        int m = m0 + wm + i * 16 + mr + r;
        float v = acc[i][j][r] + bv;
        if (relu_flag) v = fmaxf(v, 0.f);
        Cg[(size_t)m * N + n] = f2bf(v);
      }
    }
  }
}

// ---------------- rowwise LayerNorm * gain + beta, ReLU, in-place on bf16
// blockDim = N/8; grp = row / rows_per_group selects gain/beta row
__global__ __launch_bounds__(256) void ln_affine_relu(
    u16* __restrict__ H, const float* __restrict__ gain, const float* __restrict__ beta,
    int N, int rows_per_group) {
  __shared__ float red[4];
  size_t row = blockIdx.x;
  int grp = (int)(row / (size_t)rows_per_group);
  u16* hp = H + row * N;
  const float* gp = gain + (size_t)grp * N;
  const float* bp = beta + (size_t)grp * N;
  int tid = threadIdx.x;
  int nw = blockDim.x >> 6;
  union { uint4 u; u16 s[8]; } pk;
  pk.u = *(const uint4*)(hp + tid * 8);
  float v[8], s = 0.f;
#pragma unroll
  for (int j = 0; j < 8; ++j) { v[j] = bf2f(pk.s[j]); s += v[j]; }
  for (int off = 32; off > 0; off >>= 1) s += __shfl_down(s, off, 64);
  if ((tid & 63) == 0) red[tid >> 6] = s;
  __syncthreads();
  float tot = 0.f;
  for (int i = 0; i < nw; ++i) tot += red[i];
  float mu = tot / (float)N;
  float q = 0.f;
#pragma unroll
  for (int j = 0; j < 8; ++j) { float d = v[j] - mu; q += d * d; }
  __syncthreads();
  for (int off = 32; off > 0; off >>= 1) q += __shfl_down(q, off, 64);
  if ((tid & 63) == 0) red[tid >> 6] = q;
  __syncthreads();
  tot = 0.f;
  for (int i = 0; i < nw; ++i) tot += red[i];
  float rstd = rsqrtf(tot / (float)N + 1e-5f);
  float4 ga = *(const float4*)(gp + tid * 8);
  float4 gb2 = *(const float4*)(gp + tid * 8 + 4);
  float4 ba = *(const float4*)(bp + tid * 8);
  float4 bb2 = *(const float4*)(bp + tid * 8 + 4);
  float gg[8] = { ga.x, ga.y, ga.z, ga.w, gb2.x, gb2.y, gb2.z, gb2.w };
  float bt[8] = { ba.x, ba.y, ba.z, ba.w, bb2.x, bb2.y, bb2.z, bb2.w };
  u16 o[8];
#pragma unroll
  for (int j = 0; j < 8; ++j) {
    float y = (v[j] - mu) * rstd * gg[j] + bt[j];
    o[j] = f2bf(fmaxf(y, 0.f));
  }
  *(uint4*)(hp + tid * 8) = *(uint4*)o;
}

// ---------------- pack gate weights: W[t][k][e] -> out4[k4][j][0..3], j=t*L+e
__global__ __launch_bounds__(256) void prep_gw4(
    const float* __restrict__ W, float* __restrict__ out4,
    int G, int K, int E, int L) {
  int id = blockIdx.x * 256 + threadIdx.x;
  int tot = (K >> 2) * 32;
  if (id >= tot) return;
  int k4 = id >> 5, j = id & 31;
  int t = j / L, e = j % L;
  float4 v = { 0.f, 0.f, 0.f, 0.f };
  if (t < G && e < E) {
    const float* w = W + (size_t)t * K * E + e;
    v.x = w[(size_t)(k4 * 4 + 0) * E];
    v.y = w[(size_t)(k4 * 4 + 1) * E];
    v.z = w[(size_t)(k4 * 4 + 2) * E];
    v.w = w[(size_t)(k4 * 4 + 3) * E];
  }
  *(float4*)(out4 + (size_t)id * 4) = v;
}

// ---------------- fast gates: 8 rows/block, lane j=t*L+e; unroll-8, 8 accumulators
__global__ __launch_bounds__(256) void gates_fast(
    const void* __restrict__ X, int is_bf16, long t_stride,
    const float* __restrict__ GW4, const float* __restrict__ GB,
    float* __restrict__ out, int G, int K, int E, int L) {
  int tid = threadIdx.x;
  int rl = tid >> 5;
  int j  = tid & 31;
  int t = j / L, e = j % L;
  int b = blockIdx.x * 8 + rl;
  int tr = (t < G) ? t : (G - 1);
  int K4 = K >> 2;
  float ac[8];
#pragma unroll
  for (int u = 0; u < 8; ++u) ac[u] = 0.f;
  if (is_bf16) {
    const u16* xr = (const u16*)X + (size_t)tr * t_stride + (size_t)b * K;
    for (int k4 = 0; k4 < K4; k4 += 8) {
      uint2 p[8]; float4 q[8];
#pragma unroll
      for (int u = 0; u < 8; ++u) {
        p[u] = *(const uint2*)(xr + (k4 + u) * 4);
        q[u] = *(const float4*)(GW4 + ((size_t)(k4 + u) * 32 + j) * 4);
      }
#pragma unroll
      for (int u = 0; u < 8; ++u)
        ac[u] += bf2f((u16)(p[u].x & 0xffffu)) * q[u].x + bf2f((u16)(p[u].x >> 16)) * q[u].y
               + bf2f((u16)(p[u].y & 0xffffu)) * q[u].z + bf2f((u16)(p[u].y >> 16)) * q[u].w;
    }
  } else {
    const float* xr = (const float*)X + (size_t)tr * t_stride + (size_t)b * K;
    for (int k4 = 0; k4 < K4; k4 += 8) {
      float4 xv[8]; float4 q[8];
#pragma unroll
      for (int u = 0; u < 8; ++u) {
        xv[u] = *(const float4*)(xr + (k4 + u) * 4);
        q[u] = *(const float4*)(GW4 + ((size_t)(k4 + u) * 32 + j) * 4);
      }
#pragma unroll
      for (int u = 0; u < 8; ++u)
        ac[u] += xv[u].x * q[u].x + xv[u].y * q[u].y + xv[u].z * q[u].z + xv[u].w * q[u].w;
    }
  }
  float acc = ((ac[0] + ac[1]) + (ac[2] + ac[3])) + ((ac[4] + ac[5]) + (ac[6] + ac[7]));
  bool valid = (t < G) && (e < E);
  float lg = valid ? (acc + GB[t * E + e]) : -1e30f;
  float m = lg;
  for (int o = L >> 1; o > 0; o >>= 1) m = fmaxf(m, __shfl_xor(m, o, L));
  float ex = valid ? expf(lg - m) : 0.f;
  float sm = ex;
  for (int o = L >> 1; o > 0; o >>= 1) sm += __shfl_xor(sm, o, L);
  if (valid) out[((size_t)t * B_ + b) * E + e] = ex / sm;
}

// ---------------- MMoE mixing: task_hs[t]=sum_e g[t,e]*eo[e]; shared=mean_t
__global__ __launch_bounds__(256) void mmoe_mix(
    const u16* __restrict__ eo, const float* __restrict__ gates,
    u16* __restrict__ task_hs, u16* __restrict__ shared_h) {
  __shared__ float g[24];
  int b = blockIdx.x, tid = threadIdx.x;
  if (tid < 24) g[tid] = gates[((size_t)(tid >> 3) * B_ + b) * 8 + (tid & 7)];
  __syncthreads();
  int o = tid * 2;
  float a0[3] = {0, 0, 0}, a1[3] = {0, 0, 0};
#pragma unroll
  for (int e = 0; e < 8; ++e) {
    u32 w = *(const u32*)(eo + ((size_t)e * B_ + b) * 512 + o);
    float v0 = bf2f((u16)(w & 0xffffu)), v1 = bf2f((u16)(w >> 16));
#pragma unroll
    for (int t = 0; t < 3; ++t) { a0[t] += g[t * 8 + e] * v0; a1[t] += g[t * 8 + e] * v1; }
  }
  float s0 = 0.f, s1 = 0.f;
#pragma unroll
  for (int t = 0; t < 3; ++t) {
    u16 p[2] = { f2bf(a0[t]), f2bf(a1[t]) };
    *(u32*)(task_hs + ((size_t)t * B_ + b) * 512 + o) = *(u32*)p;
    s0 += a0[t]; s1 += a1[t];
  }
  u16 p[2] = { f2bf(s0 * (1.f / 3.f)), f2bf(s1 * (1.f / 3.f)) };
  *(u32*)(shared_h + (size_t)b * 512 + o) = *(u32*)p;
}

// ---------------- CGC mixing
__global__ __launch_bounds__(256) void cgc_mix(
    const u16* __restrict__ to, const u16* __restrict__ so,
    const float* __restrict__ g, const float* __restrict__ sg,
    u16* __restrict__ task_out, u16* __restrict__ shared_out) {
  int b = blockIdx.x, o = threadIdx.x;
  float tv[9], sv[4];
#pragma unroll
  for (int j = 0; j < 9; ++j) tv[j] = bf2f(to[((size_t)j * B_ + b) * 256 + o]);
#pragma unroll
  for (int s = 0; s < 4; ++s) sv[s] = bf2f(so[((size_t)s * B_ + b) * 256 + o]);
#pragma unroll
  for (int t = 0; t < 3; ++t) {
    const float* gt = g + ((size_t)t * B_ + b) * 7;
    float a = gt[0] * tv[t * 3] + gt[1] * tv[t * 3 + 1] + gt[2] * tv[t * 3 + 2];
#pragma unroll
    for (int s = 0; s < 4; ++s) a += gt[3 + s] * sv[s];
    task_out[((size_t)t * B_ + b) * 256 + o] = f2bf(a);
  }
  if (shared_out) {
    const float* sp = sg + (size_t)b * 13;
    float a = 0.f;
#pragma unroll
    for (int j = 0; j < 9; ++j) a += sp[j] * tv[j];
#pragma unroll
    for (int s = 0; s < 4; ++s) a += sp[9 + s] * sv[s];
    shared_out[(size_t)b * 256 + o] = f2bf(a);
  }
}

// ---------------- tower head: out[t*B+b] = th[t,b,:] . w2[t,:] + b2[t]
__global__ __launch_bounds__(256) void tower_out(
    const u16* __restrict__ th, const float* __restrict__ w2,
    const float* __restrict__ b2, float* __restrict__ out) {
  int r = blockIdx.x * 4 + (threadIdx.x >> 6);
  int lane = threadIdx.x & 63;
  int t = r / B_;
  const u16* row = th + (size_t)r * 256;
  u16 hv[4];
  *(uint2*)hv = *(const uint2*)(row + lane * 4);
  float4 wv = *(const float4*)(w2 + t * 256 + lane * 4);
  float s = bf2f(hv[0]) * wv.x + bf2f(hv[1]) * wv.y + bf2f(hv[2]) * wv.z + bf2f(hv[3]) * wv.w;
  for (int off = 32; off > 0; off >>= 1) s += __shfl_down(s, off, 64);
  if (lane == 0) out[r] = s + b2[t];
}

extern "C" void kernel_launch(void* const* d_in, const int* in_sizes, int n_in,
                              void* d_out, int out_size, void* d_ws, size_t ws_size,
                              hipStream_t stream) {
  (void)in_sizes; (void)n_in; (void)out_size;
  const float* x      = (const float*)d_in[0];
  const float* m_w1   = (const float*)d_in[1];
  const float* m_b1   = (const float*)d_in[2];
  const float* m_g    = (const float*)d_in[3];
  const float* m_be   = (const float*)d_in[4];
  const float* m_w2   = (const float*)d_in[5];
  const float* m_b2   = (const float*)d_in[6];
  const float* m_gw   = (const float*)d_in[7];
  const float* m_gb   = (const float*)d_in[8];
  const float* c0_sw1 = (const float*)d_in[9];
  const float* c0_sb1 = (const float*)d_in[10];
  const float* c0_sg  = (const float*)d_in[11];
  const float* c0_sbe = (const float*)d_in[12];
  const float* c0_sw2 = (const float*)d_in[13];
  const float* c0_sb2 = (const float*)d_in[14];
  const float* c0_tw1 = (const float*)d_in[15];
  const float* c0_tb1 = (const float*)d_in[16];
  const float* c0_tg  = (const float*)d_in[17];
  const float* c0_tbe = (const float*)d_in[18];
  const float* c0_tw2 = (const float*)d_in[19];
  const float* c0_tb2 = (const float*)d_in[20];
  const float* c0_gw  = (const float*)d_in[21];
  const float* c0_gb  = (const float*)d_in[22];
  const float* c0_sgw = (const float*)d_in[23];
  const float* c0_sgb = (const float*)d_in[24];
  const float* c1_sw1 = (const float*)d_in[25];
  const float* c1_sb1 = (const float*)d_in[26];
  const float* c1_sg  = (const float*)d_in[27];
  const float* c1_sbe = (const float*)d_in[28];
  const float* c1_sw2 = (const float*)d_in[29];
  const float* c1_sb2 = (const float*)d_in[30];
  const float* c1_tw1 = (const float*)d_in[31];
  const float* c1_tb1 = (const float*)d_in[32];
  const float* c1_tg  = (const float*)d_in[33];
  const float* c1_tbe = (const float*)d_in[34];
  const float* c1_tw2 = (const float*)d_in[35];
  const float* c1_tb2 = (const float*)d_in[36];
  const float* c1_gw  = (const float*)d_in[37];
  const float* c1_gb  = (const float*)d_in[38];
  const float* tw1    = (const float*)d_in[39];
  const float* tb1    = (const float*)d_in[40];
  const float* tw2    = (const float*)d_in[41];
  const float* tb2    = (const float*)d_in[42];

  // ---- flat workspace plan, 163 MB ----
  // MMoE:      XB[0,16) W1T[16,48) W2T[48,64) HID[64,96) EO[96,160) GATES[160,163)
  // post-mix:  TASK_HS[16,40) SHARED_H[40,48)
  // CGC0:      SO0[0,16) C0W[48,67.5) HID0[68,104) TO0[104,140)
  // post-mix0: TASK1[16,28) SHARED1[28,32)
  // CGC1:      SO1[0,16) C1W[48,61) HID1[68,104) TO1[104,140)
  // post-mix1: TASK2[32,44)
  // towers:    TWT[48,48.4) TH[104,116)
  const size_t MB = 1024 * 1024;
  char* ws = (char*)d_ws;
  if (ws_size < 163 * MB) return;
  u16* XB      = (u16*)(ws);
  u16* W1T     = (u16*)(ws + 16 * MB);
  u16* W2T     = (u16*)(ws + 48 * MB);           // 16 MB (8 x 512 x 2048 bf16)
  u16* HID     = (u16*)(ws + 64 * MB);           // 32 MB (8 x 1024 x 2048 bf16)
  u16* EO      = (u16*)(ws + 96 * MB);           // 64 MB
  u16* TASK_HS = (u16*)(ws + 16 * MB);
  u16* SHARED_H= (u16*)(ws + 40 * MB);
  u16* SO0     = (u16*)(ws);
  u16* C0_SW1T = (u16*)(ws + 48 * MB);           // 4 MB
  u16* C0_SW2T = (u16*)(ws + 52 * MB);           // 2 MB
  u16* C0_TW1T = (u16*)(ws + 54 * MB);           // 9 MB
  u16* C0_TW2T = (u16*)(ws + 63 * MB);           // 4.5 MB -> ends 67.5
  u16* HID0    = (u16*)(ws + 68 * MB);           // 36 MB
  u16* TO0     = (u16*)(ws + 104 * MB);          // 36 MB
  u16* TASK1   = (u16*)(ws + 16 * MB);           // 12 MB
  u16* SHARED1 = (u16*)(ws + 28 * MB);           // 4 MB
  u16* SO1     = (u16*)(ws);                     // 16 MB
  u16* C1_SW1T = (u16*)(ws + 48 * MB);           // 2 MB
  u16* C1_SW2T = (u16*)(ws + 50 * MB);           // 2 MB
  u16* C1_TW1T = (u16*)(ws + 52 * MB);           // 4.5 MB
  u16* C1_TW2T = (u16*)(ws + 56 * MB + 512 * 1024);  // 4.5 MB -> ends 61
  u16* HID1    = (u16*)(ws + 68 * MB);
  u16* TO1     = (u16*)(ws + 104 * MB);
  u16* TASK2   = (u16*)(ws + 32 * MB);           // 12 MB
  u16* TWT     = (u16*)(ws + 48 * MB);
  u16* TH      = (u16*)(ws + 104 * MB);          // 12 MB

  float* gbase = (float*)(ws + 160 * MB);
  float* gmo  = gbase;                       // 3*B*8
  float* g0   = gmo  + (size_t)3 * B_ * 8;   // 3*B*7
  float* sg0  = g0   + (size_t)3 * B_ * 7;   // B*13
  float* g1   = sg0  + (size_t)B_ * 13;      // 3*B*7
  float* gw4a = g1   + (size_t)3 * B_ * 7;   // 32768
  float* gw4b = gw4a + 32768;

  dim3 blk(256);
  cast_bf16k<<<8192, blk, 0, stream>>>(x, XB);

  // ---- MMoE gate ----
  prep_gw4<<<32, blk, 0, stream>>>(m_gw, gw4a, 3, 1024, 8, 8);
  gates_fast<<<B_ / 8, blk, 0, stream>>>(x, 0, 0L, gw4a, m_gb, gmo, 3, 1024, 8, 8);

  // ---- MMoE: transpose all 8 experts, then 8 chunks x 1024 rows x z=8 ----
  // (R5/R6 bug: loop ran 4 chunks x 1024 = only half of B_=8192)
  transpose_cast<<<dim3(16, 32, 8), blk, 0, stream>>>(m_w1, W1T, 1024, 2048);
  transpose_cast<<<dim3(32,  8, 8), blk, 0, stream>>>(m_w2, W2T, 2048, 512);
  for (int c = 0; c < 8; ++c) {
    size_t r0 = (size_t)c * 1024;   // chunk row offset (R=1024)
    gemm_t<128><<<dim3(8, 16, 8), blk, 0, stream>>>(
        XB + r0 * 1024, 0L, 1, 0, W1T, m_b1, HID, (long)1024 * 2048, 2048, 1024, 0);
    ln_affine_relu<<<8 * 1024, 256, 0, stream>>>(HID, m_g, m_be, 2048, 1024);
    gemm_t<64><<<dim3(8, 8, 8), blk, 0, stream>>>(
        HID, (long)1024 * 2048, 1, 0, W2T, m_b2, EO + r0 * 512, (long)B_ * 512, 512, 2048, 0);
  }
  mmoe_mix<<<B_, blk, 0, stream>>>(EO, gmo, TASK_HS, SHARED_H);

  // ---- CGC0 gates ----
  prep_gw4<<<16, blk, 0, stream>>>(c0_gw, gw4a, 3, 512, 7, 8);
  prep_gw4<<<16, blk, 0, stream>>>(c0_sgw, gw4b, 1, 512, 13, 16);
  gates_fast<<<B_ / 8, blk, 0, stream>>>(TASK_HS, 1, (long)B_ * 512, gw4a, c0_gb, g0, 3, 512, 7, 8);
  gates_fast<<<B_ / 8, blk, 0, stream>>>(SHARED_H, 1, 0L, gw4b, c0_sgb, sg0, 1, 512, 13, 16);

  // ---- CGC0 ----
  transpose_cast<<<dim3( 8, 16, 4), blk, 0, stream>>>(c0_sw1, C0_SW1T, 512, 1024);
  transpose_cast<<<dim3(16,  4, 4), blk, 0, stream>>>(c0_sw2, C0_SW2T, 1024, 256);
  transpose_cast<<<dim3( 8, 16, 9), blk, 0, stream>>>(c0_tw1, C0_TW1T, 512, 1024);
  transpose_cast<<<dim3(16,  4, 9), blk, 0, stream>>>(c0_tw2, C0_TW2T, 1024, 256);
  for (int c = 0; c < 2; ++c) {   // shared experts: z=4, R=4096 (2*4096 = 8192 ✓)
    size_t r0 = (size_t)c * 4096;
    gemm_t<128><<<dim3(32, 8, 4), blk, 0, stream>>>(
        SHARED_H + r0 * 512, 0L, 1, 0, C0_SW1T, c0_sb1, HID0, (long)4096 * 1024, 1024, 512, 0);
    ln_affine_relu<<<4 * 4096, 128, 0, stream>>>(HID0, c0_sg, c0_sbe, 1024, 4096);
    gemm_t<64><<<dim3(32, 4, 4), blk, 0, stream>>>(
        HID0, (long)4096 * 1024, 1, 0, C0_SW2T, c0_sb2, SO0 + r0 * 256, (long)B_ * 256, 256, 1024, 0);
  }
  for (int c = 0; c < 4; ++c) {   // task experts: z=9, R=2048 (4*2048 = 8192 ✓)
    size_t r0 = (size_t)c * 2048;
    gemm_t<128><<<dim3(16, 8, 9), blk, 0, stream>>>(
        TASK_HS + r0 * 512, (long)B_ * 512, 3, 0, C0_TW1T, c0_tb1, HID0, (long)2048 * 1024, 1024, 512, 0);
    ln_affine_relu<<<9 * 2048, 128, 0, stream>>>(HID0, c0_tg, c0_tbe, 1024, 2048);
    gemm_t<64><<<dim3(16, 4, 9), blk, 0, stream>>>(
        HID0, (long)2048 * 1024, 1, 0, C0_TW2T, c0_tb2, TO0 + r0 * 256, (long)B_ * 256, 256, 1024, 0);
  }
  cgc_mix<<<B_, blk, 0, stream>>>(TO0, SO0, g0, sg0, TASK1, SHARED1);

  // ---- CGC1 gate ----
  prep_gw4<<<8, blk, 0, stream>>>(c1_gw, gw4a, 3, 256, 7, 8);
  gates_fast<<<B_ / 8, blk, 0, stream>>>(TASK1, 1, (long)B_ * 256, gw4a, c1_gb, g1, 3, 256, 7, 8);

  // ---- CGC1 ----
  transpose_cast<<<dim3( 4, 16, 4), blk, 0, stream>>>(c1_sw1, C1_SW1T, 256, 1024);
  transpose_cast<<<dim3(16,  4, 4), blk, 0, stream>>>(c1_sw2, C1_SW2T, 1024, 256);
  transpose_cast<<<dim3( 4, 16, 9), blk, 0, stream>>>(c1_tw1, C1_TW1T, 256, 1024);
  transpose_cast<<<dim3(16,  4, 9), blk, 0, stream>>>(c1_tw2, C1_TW2T, 1024, 256);
  for (int c = 0; c < 2; ++c) {   // shared: z=4, R=4096
    size_t r0 = (size_t)c * 4096;
    gemm_t<128><<<dim3(32, 8, 4), blk, 0, stream>>>(
        SHARED1 + r0 * 256, 0L, 1, 0, C1_SW1T, c1_sb1, HID1, (long)4096 * 1024, 1024, 256, 0);
    ln_affine_relu<<<4 * 4096, 128, 0, stream>>>(HID1, c1_sg, c1_sbe, 1024, 4096);
    gemm_t<64><<<dim3(32, 4, 4), blk, 0, stream>>>(
        HID1, (long)4096 * 1024, 1, 0, C1_SW2T, c1_sb2, SO1 + r0 * 256, (long)B_ * 256, 256, 1024, 0);
  }
  for (int c = 0; c < 4; ++c) {   // task: z=9, R=2048
    size_t r0 = (size_t)c * 2048;
    gemm_t<128><<<dim3(16, 8, 9), blk, 0, stream>>>(
        TASK1 + r0 * 256, (long)B_ * 256, 3, 0, C1_TW1T, c1_tb1, HID1, (long)2048 * 1024, 1024, 256, 0);
    ln_affine_relu<<<9 * 2048, 128, 0, stream>>>(HID1, c1_tg, c1_tbe, 1024, 2048);
    gemm_t<64><<<dim3(16, 4, 9), blk, 0, stream>>>(
        HID1, (long)2048 * 1024, 1, 0, C1_TW2T, c1_tb2, TO1 + r0 * 256, (long)B_ * 256, 256, 1024, 0);
  }
  cgc_mix<<<B_, blk, 0, stream>>>(TO1, SO1, g1, nullptr, TASK2, nullptr);

  // ---- towers ----
  transpose_cast<<<dim3(4, 4, 3), blk, 0, stream>>>(tw1, TWT, 256, 256);
  gemm_t<64><<<dim3(64, 4, 3), blk, 0, stream>>>(
      TASK2, (long)B_ * 256, 1, 0, TWT, tb1, TH, (long)B_ * 256, 256, 256, 1);
  tower_out<<<6144, blk, 0, stream>>>(TH, tw2, tb2, (float*)d_out);
}

// Round 8
// 2099.385 us; speedup vs baseline: 1.0702x; 1.0702x over previous
//
#include <hip/hip_runtime.h>

typedef unsigned short u16;
typedef unsigned int   u32;
typedef __bf16  bf16x8 __attribute__((ext_vector_type(8)));
typedef float   f32x4  __attribute__((ext_vector_type(4)));

#define B_ 8192
#define DI __device__ __forceinline__

DI u16 f2bf(float f) {
  u32 u = __float_as_uint(f);
  u = (u + 0x7fffu + ((u >> 16) & 1u)) >> 16;   // RNE
  return (u16)u;
}
DI float bf2f(u16 h) { return __uint_as_float(((u32)h) << 16); }

// async global->LDS, 16B per lane; LDS dest = wave-uniform base + lane*16
DI void gll(const u16* g, u16* l) {
  __builtin_amdgcn_global_load_lds(
      (const __attribute__((address_space(1))) void*)g,
      (__attribute__((address_space(3))) void*)l, 16, 0, 0);
}

// ---------------- weight transpose + cast: W[g][K][N] f32 -> Wt[g][N][K] bf16
__global__ __launch_bounds__(256) void transpose_cast(
    const float* __restrict__ W, u16* __restrict__ Wt, int K, int N) {
  __shared__ float tile[64][65];
  int g = blockIdx.z;
  int k0 = blockIdx.x * 64, n0 = blockIdx.y * 64;
  const float* Wg = W + (size_t)g * K * N;
  u16* Og = Wt + (size_t)g * N * K;
  int tid = threadIdx.x;
  int rr = tid >> 4, cc = (tid & 15) * 4;
#pragma unroll
  for (int r = 0; r < 4; ++r) {
    int k = rr + r * 16;
    float4 v = *(const float4*)(Wg + (size_t)(k0 + k) * N + n0 + cc);
    tile[k][cc] = v.x; tile[k][cc + 1] = v.y; tile[k][cc + 2] = v.z; tile[k][cc + 3] = v.w;
  }
  __syncthreads();
  int nr = tid >> 3, kc = (tid & 7) * 8;
#pragma unroll
  for (int p = 0; p < 2; ++p) {
    int n = nr + p * 32;
    u16 tmp[8];
#pragma unroll
    for (int j = 0; j < 8; ++j) tmp[j] = f2bf(tile[kc + j][n]);
    *(uint4*)(Og + (size_t)(n0 + n) * K + k0 + kc) = *(uint4*)tmp;
  }
}

// ---------------- f32 -> bf16 cast (4 elems/thread)
__global__ __launch_bounds__(256) void cast_bf16k(const float* __restrict__ X, u16* __restrict__ Y) {
  size_t i = ((size_t)blockIdx.x * 256 + threadIdx.x) * 4;
  float4 v = *(const float4*)(X + i);
  u16 t[4] = { f2bf(v.x), f2bf(v.y), f2bf(v.z), f2bf(v.w) };
  *(uint2*)(Y + i) = *(uint2*)t;
}

// ---------------- batched bf16 GEMM, templated N-tile (128 or 64)
// Double-buffered LDS (async prefetch overlaps compute) + XOR bank swizzle.
// LDS layout: rows of 32 u16 (64 B = 4 chunks of 16 B); row r's global chunk c
// is stored at LDS chunk c ^ ((r>>1)&3) -> fragment reads are 2-way (free).
// nk = K/32 must be EVEN (true for all K used here: 256..2048).
#define BM 128
#define BK 32
#define LDK 32

template<int BN_>
__global__ __launch_bounds__(256) void gemm_t(
    const u16* __restrict__ A, long a_stride, int a_div, int a_g0,
    const u16* __restrict__ Wt, const float* __restrict__ bias,
    u16* __restrict__ C, long c_stride, int N, int K, int relu_flag) {
  constexpr int JT = BN_ / 32;       // B sub-tiles per wave (4 or 2)
  constexpr int BROWS = BN_ / 4;     // B rows staged per wave (32 or 16)
  int gz = blockIdx.z;
  const u16* Ag = A + (size_t)((a_g0 + gz) / a_div) * a_stride;
  const u16* Wg = Wt + (size_t)gz * N * K;
  u16* Cg = C + (size_t)gz * c_stride;
  int m0 = blockIdx.x * BM, n0 = blockIdx.y * BN_;

  __shared__ __align__(16) u16 As0[BM * LDK];
  __shared__ __align__(16) u16 As1[BM * LDK];
  __shared__ __align__(16) u16 Bs0[BN_ * LDK];
  __shared__ __align__(16) u16 Bs1[BN_ * LDK];

  int tid = threadIdx.x;
  int wv = tid >> 6, ln = tid & 63;
  int wm = (wv >> 1) * 64, wn = (wv & 1) * (BN_ / 2);
  int lr = ln & 15;
  int lk = ((ln >> 4) ^ ((ln >> 1) & 3)) * 8;   // swizzled read col (global chunk ln>>4)

  int sr = ln >> 2;                              // staged row within 16-row block
  int sc = (((ln & 3) ^ ((ln >> 3) & 3))) * 8;   // swizzled stage col
  const u16* aG = Ag + (size_t)(m0 + wv * 32 + sr) * K + sc;
  const u16* bG = Wg + (size_t)(n0 + wv * BROWS + sr) * K + sc;
  const int aOff = (wv * 32) * LDK;              // wave-uniform LDS bases
  const int bOff = (wv * BROWS) * LDK;

  f32x4 acc[4][JT];
#pragma unroll
  for (int i = 0; i < 4; ++i)
#pragma unroll
    for (int j = 0; j < JT; ++j)
      acc[i][j] = (f32x4){0.f, 0.f, 0.f, 0.f};

  auto stage = [&](u16* As, u16* Bs, int ks) {
    const u16* aP = aG + ks * BK;
    const u16* bP = bG + ks * BK;
    gll(aP, As + aOff);
    gll(aP + (size_t)16 * K, As + aOff + 16 * LDK);
    gll(bP, Bs + bOff);
    if (BN_ == 128) gll(bP + (size_t)16 * K, Bs + bOff + 16 * LDK);
  };
  auto compute = [&](const u16* As, const u16* Bs) {
    bf16x8 af[4], bfr[JT];
#pragma unroll
    for (int i = 0; i < 4; ++i) {
      union { uint4 u; bf16x8 v; } ua;
      ua.u = *(const uint4*)(As + (wm + i * 16 + lr) * LDK + lk);
      af[i] = ua.v;
    }
#pragma unroll
    for (int j = 0; j < JT; ++j) {
      union { uint4 u; bf16x8 v; } ub;
      ub.u = *(const uint4*)(Bs + (wn + j * 16 + lr) * LDK + lk);
      bfr[j] = ub.v;
    }
#pragma unroll
    for (int i = 0; i < 4; ++i)
#pragma unroll
      for (int j = 0; j < JT; ++j)
        acc[i][j] = __builtin_amdgcn_mfma_f32_16x16x32_bf16(af[i], bfr[j], acc[i][j], 0, 0, 0);
  };

  int nk = K / BK;                 // even
  stage(As0, Bs0, 0);
  __syncthreads();                 // drains prologue loads
  for (int ks = 0; ks < nk; ks += 2) {
    stage(As1, Bs1, ks + 1);       // prefetch next (in flight during compute)
    compute(As0, Bs0);
    __syncthreads();               // drains As1/Bs1 loads; readers of As0 done
    if (ks + 2 < nk) stage(As0, Bs0, ks + 2);
    compute(As1, Bs1);
    __syncthreads();
  }

  // epilogue: D row = (lane>>4)*4+reg, col = lane&15
  int mr = (ln >> 4) * 4;
#pragma unroll
  for (int i = 0; i < 4; ++i) {
#pragma unroll
    for (int j = 0; j < JT; ++j) {
      int n = n0 + wn + j * 16 + lr;
      float bv = bias[(size_t)gz * N + n];
#pragma unroll
      for (int r = 0; r < 4; ++r) {
        int m = m0 + wm + i * 16 + mr + r;
        float v = acc[i][j][r] + bv;
        if (relu_flag) v = fmaxf(v, 0.f);
        Cg[(size_t)m * N + n] = f2bf(v);
      }
    }
  }
}

// ---------------- rowwise LayerNorm * gain + beta, ReLU, in-place on bf16
// blockDim = N/8; grp = row / rows_per_group selects gain/beta row
__global__ __launch_bounds__(256) void ln_affine_relu(
    u16* __restrict__ H, const float* __restrict__ gain, const float* __restrict__ beta,
    int N, int rows_per_group) {
  __shared__ float red[4];
  size_t row = blockIdx.x;
  int grp = (int)(row / (size_t)rows_per_group);
  u16* hp = H + row * N;
  const float* gp = gain + (size_t)grp * N;
  const float* bp = beta + (size_t)grp * N;
  int tid = threadIdx.x;
  int nw = blockDim.x >> 6;
  union { uint4 u; u16 s[8]; } pk;
  pk.u = *(const uint4*)(hp + tid * 8);
  float v[8], s = 0.f;
#pragma unroll
  for (int j = 0; j < 8; ++j) { v[j] = bf2f(pk.s[j]); s += v[j]; }
  for (int off = 32; off > 0; off >>= 1) s += __shfl_down(s, off, 64);
  if ((tid & 63) == 0) red[tid >> 6] = s;
  __syncthreads();
  float tot = 0.f;
  for (int i = 0; i < nw; ++i) tot += red[i];
  float mu = tot / (float)N;
  float q = 0.f;
#pragma unroll
  for (int j = 0; j < 8; ++j) { float d = v[j] - mu; q += d * d; }
  __syncthreads();
  for (int off = 32; off > 0; off >>= 1) q += __shfl_down(q, off, 64);
  if ((tid & 63) == 0) red[tid >> 6] = q;
  __syncthreads();
  tot = 0.f;
  for (int i = 0; i < nw; ++i) tot += red[i];
  float rstd = rsqrtf(tot / (float)N + 1e-5f);
  float4 ga = *(const float4*)(gp + tid * 8);
  float4 gb2 = *(const float4*)(gp + tid * 8 + 4);
  float4 ba = *(const float4*)(bp + tid * 8);
  float4 bb2 = *(const float4*)(bp + tid * 8 + 4);
  float gg[8] = { ga.x, ga.y, ga.z, ga.w, gb2.x, gb2.y, gb2.z, gb2.w };
  float bt[8] = { ba.x, ba.y, ba.z, ba.w, bb2.x, bb2.y, bb2.z, bb2.w };
  u16 o[8];
#pragma unroll
  for (int j = 0; j < 8; ++j) {
    float y = (v[j] - mu) * rstd * gg[j] + bt[j];
    o[j] = f2bf(fmaxf(y, 0.f));
  }
  *(uint4*)(hp + tid * 8) = *(uint4*)o;
}

// ---------------- pack gate weights: W[t][k][e] -> out4[k4][j][0..3], j=t*L+e
__global__ __launch_bounds__(256) void prep_gw4(
    const float* __restrict__ W, float* __restrict__ out4,
    int G, int K, int E, int L) {
  int id = blockIdx.x * 256 + threadIdx.x;
  int tot = (K >> 2) * 32;
  if (id >= tot) return;
  int k4 = id >> 5, j = id & 31;
  int t = j / L, e = j % L;
  float4 v = { 0.f, 0.f, 0.f, 0.f };
  if (t < G && e < E) {
    const float* w = W + (size_t)t * K * E + e;
    v.x = w[(size_t)(k4 * 4 + 0) * E];
    v.y = w[(size_t)(k4 * 4 + 1) * E];
    v.z = w[(size_t)(k4 * 4 + 2) * E];
    v.w = w[(size_t)(k4 * 4 + 3) * E];
  }
  *(float4*)(out4 + (size_t)id * 4) = v;
}

// ---------------- fast gates: 8 rows/block, lane j=t*L+e; unroll-8, 8 accumulators
__global__ __launch_bounds__(256) void gates_fast(
    const void* __restrict__ X, int is_bf16, long t_stride,
    const float* __restrict__ GW4, const float* __restrict__ GB,
    float* __restrict__ out, int G, int K, int E, int L) {
  int tid = threadIdx.x;
  int rl = tid >> 5;
  int j  = tid & 31;
  int t = j / L, e = j % L;
  int b = blockIdx.x * 8 + rl;
  int tr = (t < G) ? t : (G - 1);
  int K4 = K >> 2;
  float ac[8];
#pragma unroll
  for (int u = 0; u < 8; ++u) ac[u] = 0.f;
  if (is_bf16) {
    const u16* xr = (const u16*)X + (size_t)tr * t_stride + (size_t)b * K;
    for (int k4 = 0; k4 < K4; k4 += 8) {
      uint2 p[8]; float4 q[8];
#pragma unroll
      for (int u = 0; u < 8; ++u) {
        p[u] = *(const uint2*)(xr + (k4 + u) * 4);
        q[u] = *(const float4*)(GW4 + ((size_t)(k4 + u) * 32 + j) * 4);
      }
#pragma unroll
      for (int u = 0; u < 8; ++u)
        ac[u] += bf2f((u16)(p[u].x & 0xffffu)) * q[u].x + bf2f((u16)(p[u].x >> 16)) * q[u].y
               + bf2f((u16)(p[u].y & 0xffffu)) * q[u].z + bf2f((u16)(p[u].y >> 16)) * q[u].w;
    }
  } else {
    const float* xr = (const float*)X + (size_t)tr * t_stride + (size_t)b * K;
    for (int k4 = 0; k4 < K4; k4 += 8) {
      float4 xv[8]; float4 q[8];
#pragma unroll
      for (int u = 0; u < 8; ++u) {
        xv[u] = *(const float4*)(xr + (k4 + u) * 4);
        q[u] = *(const float4*)(GW4 + ((size_t)(k4 + u) * 32 + j) * 4);
      }
#pragma unroll
      for (int u = 0; u < 8; ++u)
        ac[u] += xv[u].x * q[u].x + xv[u].y * q[u].y + xv[u].z * q[u].z + xv[u].w * q[u].w;
    }
  }
  float acc = ((ac[0] + ac[1]) + (ac[2] + ac[3])) + ((ac[4] + ac[5]) + (ac[6] + ac[7]));
  bool valid = (t < G) && (e < E);
  float lg = valid ? (acc + GB[t * E + e]) : -1e30f;
  float m = lg;
  for (int o = L >> 1; o > 0; o >>= 1) m = fmaxf(m, __shfl_xor(m, o, L));
  float ex = valid ? expf(lg - m) : 0.f;
  float sm = ex;
  for (int o = L >> 1; o > 0; o >>= 1) sm += __shfl_xor(sm, o, L);
  if (valid) out[((size_t)t * B_ + b) * E + e] = ex / sm;
}

// ---------------- MMoE mixing: task_hs[t]=sum_e g[t,e]*eo[e]; shared=mean_t
__global__ __launch_bounds__(256) void mmoe_mix(
    const u16* __restrict__ eo, const float* __restrict__ gates,
    u16* __restrict__ task_hs, u16* __restrict__ shared_h) {
  __shared__ float g[24];
  int b = blockIdx.x, tid = threadIdx.x;
  if (tid < 24) g[tid] = gates[((size_t)(tid >> 3) * B_ + b) * 8 + (tid & 7)];
  __syncthreads();
  int o = tid * 2;
  float a0[3] = {0, 0, 0}, a1[3] = {0, 0, 0};
#pragma unroll
  for (int e = 0; e < 8; ++e) {
    u32 w = *(const u32*)(eo + ((size_t)e * B_ + b) * 512 + o);
    float v0 = bf2f((u16)(w & 0xffffu)), v1 = bf2f((u16)(w >> 16));
#pragma unroll
    for (int t = 0; t < 3; ++t) { a0[t] += g[t * 8 + e] * v0; a1[t] += g[t * 8 + e] * v1; }
  }
  float s0 = 0.f, s1 = 0.f;
#pragma unroll
  for (int t = 0; t < 3; ++t) {
    u16 p[2] = { f2bf(a0[t]), f2bf(a1[t]) };
    *(u32*)(task_hs + ((size_t)t * B_ + b) * 512 + o) = *(u32*)p;
    s0 += a0[t]; s1 += a1[t];
  }
  u16 p[2] = { f2bf(s0 * (1.f / 3.f)), f2bf(s1 * (1.f / 3.f)) };
  *(u32*)(shared_h + (size_t)b * 512 + o) = *(u32*)p;
}

// ---------------- CGC mixing
__global__ __launch_bounds__(256) void cgc_mix(
    const u16* __restrict__ to, const u16* __restrict__ so,
    const float* __restrict__ g, const float* __restrict__ sg,
    u16* __restrict__ task_out, u16* __restrict__ shared_out) {
  int b = blockIdx.x, o = threadIdx.x;
  float tv[9], sv[4];
#pragma unroll
  for (int j = 0; j < 9; ++j) tv[j] = bf2f(to[((size_t)j * B_ + b) * 256 + o]);
#pragma unroll
  for (int s = 0; s < 4; ++s) sv[s] = bf2f(so[((size_t)s * B_ + b) * 256 + o]);
#pragma unroll
  for (int t = 0; t < 3; ++t) {
    const float* gt = g + ((size_t)t * B_ + b) * 7;
    float a = gt[0] * tv[t * 3] + gt[1] * tv[t * 3 + 1] + gt[2] * tv[t * 3 + 2];
#pragma unroll
    for (int s = 0; s < 4; ++s) a += gt[3 + s] * sv[s];
    task_out[((size_t)t * B_ + b) * 256 + o] = f2bf(a);
  }
  if (shared_out) {
    const float* sp = sg + (size_t)b * 13;
    float a = 0.f;
#pragma unroll
    for (int j = 0; j < 9; ++j) a += sp[j] * tv[j];
#pragma unroll
    for (int s = 0; s < 4; ++s) a += sp[9 + s] * sv[s];
    shared_out[(size_t)b * 256 + o] = f2bf(a);
  }
}

// ---------------- tower head: out[t*B+b] = th[t,b,:] . w2[t,:] + b2[t]
__global__ __launch_bounds__(256) void tower_out(
    const u16* __restrict__ th, const float* __restrict__ w2,
    const float* __restrict__ b2, float* __restrict__ out) {
  int r = blockIdx.x * 4 + (threadIdx.x >> 6);
  int lane = threadIdx.x & 63;
  int t = r / B_;
  const u16* row = th + (size_t)r * 256;
  u16 hv[4];
  *(uint2*)hv = *(const uint2*)(row + lane * 4);
  float4 wv = *(const float4*)(w2 + t * 256 + lane * 4);
  float s = bf2f(hv[0]) * wv.x + bf2f(hv[1]) * wv.y + bf2f(hv[2]) * wv.z + bf2f(hv[3]) * wv.w;
  for (int off = 32; off > 0; off >>= 1) s += __shfl_down(s, off, 64);
  if (lane == 0) out[r] = s + b2[t];
}

extern "C" void kernel_launch(void* const* d_in, const int* in_sizes, int n_in,
                              void* d_out, int out_size, void* d_ws, size_t ws_size,
                              hipStream_t stream) {
  (void)in_sizes; (void)n_in; (void)out_size;
  const float* x      = (const float*)d_in[0];
  const float* m_w1   = (const float*)d_in[1];
  const float* m_b1   = (const float*)d_in[2];
  const float* m_g    = (const float*)d_in[3];
  const float* m_be   = (const float*)d_in[4];
  const float* m_w2   = (const float*)d_in[5];
  const float* m_b2   = (const float*)d_in[6];
  const float* m_gw   = (const float*)d_in[7];
  const float* m_gb   = (const float*)d_in[8];
  const float* c0_sw1 = (const float*)d_in[9];
  const float* c0_sb1 = (const float*)d_in[10];
  const float* c0_sg  = (const float*)d_in[11];
  const float* c0_sbe = (const float*)d_in[12];
  const float* c0_sw2 = (const float*)d_in[13];
  const float* c0_sb2 = (const float*)d_in[14];
  const float* c0_tw1 = (const float*)d_in[15];
  const float* c0_tb1 = (const float*)d_in[16];
  const float* c0_tg  = (const float*)d_in[17];
  const float* c0_tbe = (const float*)d_in[18];
  const float* c0_tw2 = (const float*)d_in[19];
  const float* c0_tb2 = (const float*)d_in[20];
  const float* c0_gw  = (const float*)d_in[21];
  const float* c0_gb  = (const float*)d_in[22];
  const float* c0_sgw = (const float*)d_in[23];
  const float* c0_sgb = (const float*)d_in[24];
  const float* c1_sw1 = (const float*)d_in[25];
  const float* c1_sb1 = (const float*)d_in[26];
  const float* c1_sg  = (const float*)d_in[27];
  const float* c1_sbe = (const float*)d_in[28];
  const float* c1_sw2 = (const float*)d_in[29];
  const float* c1_sb2 = (const float*)d_in[30];
  const float* c1_tw1 = (const float*)d_in[31];
  const float* c1_tb1 = (const float*)d_in[32];
  const float* c1_tg  = (const float*)d_in[33];
  const float* c1_tbe = (const float*)d_in[34];
  const float* c1_tw2 = (const float*)d_in[35];
  const float* c1_tb2 = (const float*)d_in[36];
  const float* c1_gw  = (const float*)d_in[37];
  const float* c1_gb  = (const float*)d_in[38];
  const float* tw1    = (const float*)d_in[39];
  const float* tb1    = (const float*)d_in[40];
  const float* tw2    = (const float*)d_in[41];
  const float* tb2    = (const float*)d_in[42];

  // ---- flat workspace plan, 163 MB ----
  // MMoE:      XB[0,16) W1T[16,48) W2T[48,64) HID[64,96) EO[96,160) GATES[160,163)
  // post-mix:  TASK_HS[16,40) SHARED_H[40,48)
  // CGC0:      SO0[0,16) C0W[48,67.5) HID0[68,104) TO0[104,140)
  // post-mix0: TASK1[16,28) SHARED1[28,32)
  // CGC1:      SO1[0,16) C1W[48,61) HID1[68,104) TO1[104,140)
  // post-mix1: TASK2[32,44)
  // towers:    TWT[48,48.4) TH[104,116)
  const size_t MB = 1024 * 1024;
  char* ws = (char*)d_ws;
  if (ws_size < 163 * MB) return;
  u16* XB      = (u16*)(ws);
  u16* W1T     = (u16*)(ws + 16 * MB);
  u16* W2T     = (u16*)(ws + 48 * MB);           // 16 MB (8 x 512 x 2048 bf16)
  u16* HID     = (u16*)(ws + 64 * MB);           // 32 MB (8 x 1024 x 2048 bf16)
  u16* EO      = (u16*)(ws + 96 * MB);           // 64 MB
  u16* TASK_HS = (u16*)(ws + 16 * MB);
  u16* SHARED_H= (u16*)(ws + 40 * MB);
  u16* SO0     = (u16*)(ws);
  u16* C0_SW1T = (u16*)(ws + 48 * MB);           // 4 MB
  u16* C0_SW2T = (u16*)(ws + 52 * MB);           // 2 MB
  u16* C0_TW1T = (u16*)(ws + 54 * MB);           // 9 MB
  u16* C0_TW2T = (u16*)(ws + 63 * MB);           // 4.5 MB -> ends 67.5
  u16* HID0    = (u16*)(ws + 68 * MB);           // 36 MB
  u16* TO0     = (u16*)(ws + 104 * MB);          // 36 MB
  u16* TASK1   = (u16*)(ws + 16 * MB);           // 12 MB
  u16* SHARED1 = (u16*)(ws + 28 * MB);           // 4 MB
  u16* SO1     = (u16*)(ws);                     // 16 MB
  u16* C1_SW1T = (u16*)(ws + 48 * MB);           // 2 MB
  u16* C1_SW2T = (u16*)(ws + 50 * MB);           // 2 MB
  u16* C1_TW1T = (u16*)(ws + 52 * MB);           // 4.5 MB
  u16* C1_TW2T = (u16*)(ws + 56 * MB + 512 * 1024);  // 4.5 MB -> ends 61
  u16* HID1    = (u16*)(ws + 68 * MB);
  u16* TO1     = (u16*)(ws + 104 * MB);
  u16* TASK2   = (u16*)(ws + 32 * MB);           // 12 MB
  u16* TWT     = (u16*)(ws + 48 * MB);
  u16* TH      = (u16*)(ws + 104 * MB);          // 12 MB

  float* gbase = (float*)(ws + 160 * MB);
  float* gmo  = gbase;                       // 3*B*8
  float* g0   = gmo  + (size_t)3 * B_ * 8;   // 3*B*7
  float* sg0  = g0   + (size_t)3 * B_ * 7;   // B*13
  float* g1   = sg0  + (size_t)B_ * 13;      // 3*B*7
  float* gw4a = g1   + (size_t)3 * B_ * 7;   // 32768
  float* gw4b = gw4a + 32768;

  dim3 blk(256);
  cast_bf16k<<<8192, blk, 0, stream>>>(x, XB);

  // ---- MMoE gate ----
  prep_gw4<<<32, blk, 0, stream>>>(m_gw, gw4a, 3, 1024, 8, 8);
  gates_fast<<<B_ / 8, blk, 0, stream>>>(x, 0, 0L, gw4a, m_gb, gmo, 3, 1024, 8, 8);

  // ---- MMoE: transpose all 8 experts, then 8 chunks x 1024 rows x z=8 ----
  transpose_cast<<<dim3(16, 32, 8), blk, 0, stream>>>(m_w1, W1T, 1024, 2048);
  transpose_cast<<<dim3(32,  8, 8), blk, 0, stream>>>(m_w2, W2T, 2048, 512);
  for (int c = 0; c < 8; ++c) {
    size_t r0 = (size_t)c * 1024;   // chunk row offset (R=1024)
    gemm_t<128><<<dim3(8, 16, 8), blk, 0, stream>>>(
        XB + r0 * 1024, 0L, 1, 0, W1T, m_b1, HID, (long)1024 * 2048, 2048, 1024, 0);
    ln_affine_relu<<<8 * 1024, 256, 0, stream>>>(HID, m_g, m_be, 2048, 1024);
    gemm_t<64><<<dim3(8, 8, 8), blk, 0, stream>>>(
        HID, (long)1024 * 2048, 1, 0, W2T, m_b2, EO + r0 * 512, (long)B_ * 512, 512, 2048, 0);
  }
  mmoe_mix<<<B_, blk, 0, stream>>>(EO, gmo, TASK_HS, SHARED_H);

  // ---- CGC0 gates ----
  prep_gw4<<<16, blk, 0, stream>>>(c0_gw, gw4a, 3, 512, 7, 8);
  prep_gw4<<<16, blk, 0, stream>>>(c0_sgw, gw4b, 1, 512, 13, 16);
  gates_fast<<<B_ / 8, blk, 0, stream>>>(TASK_HS, 1, (long)B_ * 512, gw4a, c0_gb, g0, 3, 512, 7, 8);
  gates_fast<<<B_ / 8, blk, 0, stream>>>(SHARED_H, 1, 0L, gw4b, c0_sgb, sg0, 1, 512, 13, 16);

  // ---- CGC0 ----
  transpose_cast<<<dim3( 8, 16, 4), blk, 0, stream>>>(c0_sw1, C0_SW1T, 512, 1024);
  transpose_cast<<<dim3(16,  4, 4), blk, 0, stream>>>(c0_sw2, C0_SW2T, 1024, 256);
  transpose_cast<<<dim3( 8, 16, 9), blk, 0, stream>>>(c0_tw1, C0_TW1T, 512, 1024);
  transpose_cast<<<dim3(16,  4, 9), blk, 0, stream>>>(c0_tw2, C0_TW2T, 1024, 256);
  for (int c = 0; c < 2; ++c) {   // shared experts: z=4, R=4096
    size_t r0 = (size_t)c * 4096;
    gemm_t<128><<<dim3(32, 8, 4), blk, 0, stream>>>(
        SHARED_H + r0 * 512, 0L, 1, 0, C0_SW1T, c0_sb1, HID0, (long)4096 * 1024, 1024, 512, 0);
    ln_affine_relu<<<4 * 4096, 128, 0, stream>>>(HID0, c0_sg, c0_sbe, 1024, 4096);
    gemm_t<64><<<dim3(32, 4, 4), blk, 0, stream>>>(
        HID0, (long)4096 * 1024, 1, 0, C0_SW2T, c0_sb2, SO0 + r0 * 256, (long)B_ * 256, 256, 1024, 0);
  }
  for (int c = 0; c < 4; ++c) {   // task experts: z=9, R=2048
    size_t r0 = (size_t)c * 2048;
    gemm_t<128><<<dim3(16, 8, 9), blk, 0, stream>>>(
        TASK_HS + r0 * 512, (long)B_ * 512, 3, 0, C0_TW1T, c0_tb1, HID0, (long)2048 * 1024, 1024, 512, 0);
    ln_affine_relu<<<9 * 2048, 128, 0, stream>>>(HID0, c0_tg, c0_tbe, 1024, 2048);
    gemm_t<64><<<dim3(16, 4, 9), blk, 0, stream>>>(
        HID0, (long)2048 * 1024, 1, 0, C0_TW2T, c0_tb2, TO0 + r0 * 256, (long)B_ * 256, 256, 1024, 0);
  }
  cgc_mix<<<B_, blk, 0, stream>>>(TO0, SO0, g0, sg0, TASK1, SHARED1);

  // ---- CGC1 gate ----
  prep_gw4<<<8, blk, 0, stream>>>(c1_gw, gw4a, 3, 256, 7, 8);
  gates_fast<<<B_ / 8, blk, 0, stream>>>(TASK1, 1, (long)B_ * 256, gw4a, c1_gb, g1, 3, 256, 7, 8);

  // ---- CGC1 ----
  transpose_cast<<<dim3( 4, 16, 4), blk, 0, stream>>>(c1_sw1, C1_SW1T, 256, 1024);
  transpose_cast<<<dim3(16,  4, 4), blk, 0, stream>>>(c1_sw2, C1_SW2T, 1024, 256);
  transpose_cast<<<dim3( 4, 16, 9), blk, 0, stream>>>(c1_tw1, C1_TW1T, 256, 1024);
  transpose_cast<<<dim3(16,  4, 9), blk, 0, stream>>>(c1_tw2, C1_TW2T, 1024, 256);
  for (int c = 0; c < 2; ++c) {   // shared: z=4, R=4096
    size_t r0 = (size_t)c * 4096;
    gemm_t<128><<<dim3(32, 8, 4), blk, 0, stream>>>(
        SHARED1 + r0 * 256, 0L, 1, 0, C1_SW1T, c1_sb1, HID1, (long)4096 * 1024, 1024, 256, 0);
    ln_affine_relu<<<4 * 4096, 128, 0, stream>>>(HID1, c1_sg, c1_sbe, 1024, 4096);
    gemm_t<64><<<dim3(32, 4, 4), blk, 0, stream>>>(
        HID1, (long)4096 * 1024, 1, 0, C1_SW2T, c1_sb2, SO1 + r0 * 256, (long)B_ * 256, 256, 1024, 0);
  }
  for (int c = 0; c < 4; ++c) {   // task: z=9, R=2048
    size_t r0 = (size_t)c * 2048;
    gemm_t<128><<<dim3(16, 8, 9), blk, 0, stream>>>(
        TASK1 + r0 * 256, (long)B_ * 256, 3, 0, C1_TW1T, c1_tb1, HID1, (long)2048 * 1024, 1024, 256, 0);
    ln_affine_relu<<<9 * 2048, 128, 0, stream>>>(HID1, c1_tg, c1_tbe, 1024, 2048);
    gemm_t<64><<<dim3(16, 4, 9), blk, 0, stream>>>(
        HID1, (long)2048 * 1024, 1, 0, C1_TW2T, c1_tb2, TO1 + r0 * 256, (long)B_ * 256, 256, 1024, 0);
  }
  cgc_mix<<<B_, blk, 0, stream>>>(TO1, SO1, g1, nullptr, TASK2, nullptr);

  // ---- towers ----
  transpose_cast<<<dim3(4, 4, 3), blk, 0, stream>>>(tw1, TWT, 256, 256);
  gemm_t<64><<<dim3(64, 4, 3), blk, 0, stream>>>(
      TASK2, (long)B_ * 256, 1, 0, TWT, tb1, TH, (long)B_ * 256, 256, 256, 1);
  tower_out<<<6144, blk, 0, stream>>>(TH, tw2, tb2, (float*)d_out);
}